// Round 3
// baseline (176.244 us; speedup 1.0000x reference)
//
#include <hip/hip_runtime.h>

typedef __bf16 bf16;
typedef __bf16 bf16x4 __attribute__((ext_vector_type(4)));
typedef __bf16 bf16x8 __attribute__((ext_vector_type(8)));
typedef float f32x4 __attribute__((ext_vector_type(4)));

#define MFMA16(a, b, c) __builtin_amdgcn_mfma_f32_16x16x32_bf16((a), (b), (c), 0, 0, 0)

__device__ __forceinline__ int swz16(int r, int c) { return (c ^ (r & 15)); }
__device__ __forceinline__ int swz8(int r, int c) { return (c ^ (r & 7)); }

// ---------------- batched transpose to bf16: out[z][c][r] = (bf16)in[z][r][c] -------
template <typename T>
__global__ __launch_bounds__(256) void tr_to_bf16_kernel(
    const T* __restrict__ in, bf16* __restrict__ out, int R, int C) {
  __shared__ bf16 tile[32][33];
  const size_t mat = (size_t)blockIdx.z * R * C;
  const T* ib = in + mat;
  bf16* ob = out + mat;
  int r0 = blockIdx.x * 32, c0 = blockIdx.y * 32;
  int tx = threadIdx.x & 31, ty = threadIdx.x >> 5;
#pragma unroll
  for (int i = 0; i < 4; ++i) {
    int r = ty + i * 8;
    tile[r][tx] = (bf16)(float)ib[(size_t)(r0 + r) * C + (c0 + tx)];
  }
  __syncthreads();
#pragma unroll
  for (int i = 0; i < 4; ++i) {
    int r = ty + i * 8;
    ob[(size_t)(c0 + r) * R + (r0 + tx)] = tile[tx][r];
  }
}

// -------- QKV projection: fp32 x [4096x128] @ Wt -> Q/K [bh][t][d], V [bh][d][t] ----
__global__ __launch_bounds__(256) void proj_gemm(
    const float* __restrict__ x, const bf16* __restrict__ Wqt,
    const bf16* __restrict__ Wkt, const bf16* __restrict__ Wvt,
    bf16* __restrict__ Qb, bf16* __restrict__ Kb, bf16* __restrict__ Vt) {
  __shared__ __align__(16) bf16 As[128 * 128];
  __shared__ __align__(16) bf16 Bs[128 * 128];
  const int mt = blockIdx.x;  // 32 tiles of 128 token-rows
  const int nt = blockIdx.y;  // 24 tiles of 128 cols (8 per matrix)
  const int matid = nt >> 3, h = nt & 7;
  const bf16* W = (matid == 0) ? Wqt : (matid == 1) ? Wkt : Wvt;
  const int tid = threadIdx.x;
  const bf16* sb = W + (size_t)h * 128 * 128;  // Wt rows = output col n, 128 k each
#pragma unroll
  for (int i = 0; i < 8; ++i) {  // stage x tile, fp32 -> bf16
    int c = tid + i * 256;
    int r = c >> 4, cc = c & 15;
    const f32x4* p = (const f32x4*)(x + (size_t)(mt * 128 + r) * 128 + cc * 8);
    f32x4 a = p[0], b = p[1];
    bf16x8 o;
#pragma unroll
    for (int j = 0; j < 4; ++j) { o[j] = (bf16)a[j]; o[4 + j] = (bf16)b[j]; }
    *(bf16x8*)&As[r * 128 + swz16(r, cc) * 8] = o;
  }
#pragma unroll
  for (int i = 0; i < 8; ++i) {
    int c = tid + i * 256;
    int r = c >> 4, cc = c & 15;
    *(bf16x8*)&Bs[r * 128 + swz16(r, cc) * 8] = *(const bf16x8*)(sb + (size_t)r * 128 + cc * 8);
  }
  __syncthreads();
  const int wave = tid >> 6, lane = tid & 63;
  const int wr = (wave >> 1) * 64, wc = (wave & 1) * 64;
  const int lr = lane & 15, lkb = lane >> 4;
  const f32x4 FZ = {0.f, 0.f, 0.f, 0.f};
  f32x4 acc[4][4];
#pragma unroll
  for (int mf = 0; mf < 4; ++mf)
#pragma unroll
    for (int nf = 0; nf < 4; ++nf) acc[mf][nf] = FZ;
#pragma unroll
  for (int ks = 0; ks < 4; ++ks) {
    bf16x8 a[4], b[4];
#pragma unroll
    for (int mf = 0; mf < 4; ++mf) {
      int r = wr + mf * 16 + lr;
      a[mf] = *(const bf16x8*)&As[r * 128 + swz16(r, ks * 4 + lkb) * 8];
    }
#pragma unroll
    for (int nf = 0; nf < 4; ++nf) {
      int r = wc + nf * 16 + lr;
      b[nf] = *(const bf16x8*)&Bs[r * 128 + swz16(r, ks * 4 + lkb) * 8];
    }
#pragma unroll
    for (int mf = 0; mf < 4; ++mf)
#pragma unroll
      for (int nf = 0; nf < 4; ++nf) acc[mf][nf] = MFMA16(a[mf], b[nf], acc[mf][nf]);
  }
  const int rb = lkb * 4;
  if (matid < 2) {  // Q/K: [bh][t][d]
    bf16* Out = (matid == 0) ? Qb : Kb;
#pragma unroll
    for (int mf = 0; mf < 4; ++mf)
#pragma unroll
      for (int nf = 0; nf < 4; ++nf)
#pragma unroll
        for (int r = 0; r < 4; ++r) {
          int m = mt * 128 + wr + mf * 16 + rb + r;  // global token row
          int d = wc + nf * 16 + lr;                 // head-local dim
          int bb = m >> 11, t = m & 2047;
          Out[((size_t)(bb * 8 + h) * 2048 + t) * 128 + d] = (bf16)acc[mf][nf][r];
        }
  } else {  // V: direct transpose scatter -> [bh][d][t]
#pragma unroll
    for (int mf = 0; mf < 4; ++mf)
#pragma unroll
      for (int nf = 0; nf < 4; ++nf) {
        int d = wc + nf * 16 + lr;
        int m0 = mt * 128 + wr + mf * 16 + rb;  // 4 consecutive tokens
        int bb = m0 >> 11, t0 = m0 & 2047;
        bf16x4 vv;
#pragma unroll
        for (int r = 0; r < 4; ++r) vv[r] = (bf16)acc[mf][nf][r];
        *(bf16x4*)(Vt + ((size_t)(bb * 8 + h) * 128 + d) * 2048 + t0) = vv;
      }
  }
}

// ------- causal flash attention, paired q-tiles; output written in-place over Q -----
__global__ __launch_bounds__(256) void attn_kernel(
    bf16* __restrict__ Qb, const bf16* __restrict__ Kb, const bf16* __restrict__ Vt) {
  __shared__ __align__(16) bf16 Ks[64 * 128];     // [kv j][k], swizzled chunks
  __shared__ __align__(16) bf16 Vs[128 * 64];     // [d][kv j], swizzled chunks
  __shared__ __align__(16) bf16 Ps[4 * 16 * 64];  // per-wave P tile
  const f32x4 FZ = {0.f, 0.f, 0.f, 0.f};
  const int bid = blockIdx.x;
  const int bh = bid >> 4, pid = bid & 15;
  const int qtA = 31 - pid, qtB = pid;  // complementary pair: Ta+Tb = 33 always
  const int Ta = qtA + 1;
  const bf16* Qh = Qb + (size_t)bh * 2048 * 128;
  bf16* Qw = Qb + (size_t)bh * 2048 * 128;
  const bf16* Kh = Kb + (size_t)bh * 2048 * 128;
  const bf16* Vh = Vt + (size_t)bh * 128 * 2048;
  const int tid = threadIdx.x, wave = tid >> 6, lane = tid & 63;
  const int lr = lane & 15, lkb = lane >> 4;
  const int rb = lkb * 4;
  const float SCL = 0.12751744f;  // log2(e)/sqrt(128)

  float mrun[4], lrun[4];
  f32x4 O[8];
  bf16x8 qf[4];
  int qrow = qtA * 64 + wave * 16;  // wave's absolute q-row base

#pragma unroll
  for (int r = 0; r < 4; ++r) { mrun[r] = -__builtin_inff(); lrun[r] = 0.f; }
#pragma unroll
  for (int nf = 0; nf < 8; ++nf) O[nf] = FZ;
#pragma unroll
  for (int ks = 0; ks < 4; ++ks)
    qf[ks] = *(const bf16x8*)(Qh + (size_t)(qrow + lr) * 128 + ks * 32 + lkb * 8);

  int phoff = 0;
  for (int it = 0; it < 33; ++it) {
    if (it == Ta) {  // finalize phase A (overwrite own Q rows), start phase B
#pragma unroll
      for (int r = 0; r < 4; ++r) {
        float inv = 1.f / lrun[r];
        int t = qrow + rb + r;
#pragma unroll
        for (int nf = 0; nf < 8; ++nf)
          Qw[(size_t)t * 128 + nf * 16 + lr] = (bf16)(O[nf][r] * inv);
      }
#pragma unroll
      for (int r = 0; r < 4; ++r) { mrun[r] = -__builtin_inff(); lrun[r] = 0.f; }
#pragma unroll
      for (int nf = 0; nf < 8; ++nf) O[nf] = FZ;
      qrow = qtB * 64 + wave * 16;
#pragma unroll
      for (int ks = 0; ks < 4; ++ks)
        qf[ks] = *(const bf16x8*)(Qh + (size_t)(qrow + lr) * 128 + ks * 32 + lkb * 8);
      phoff = Ta;
    }
    const int kv0 = (it - phoff) * 64;
    __syncthreads();
#pragma unroll
    for (int i = 0; i < 4; ++i) {  // stage K tile: 64 rows x 16 chunks
      int c = tid + i * 256;
      int r = c >> 4, cc = c & 15;
      *(bf16x8*)&Ks[r * 128 + swz16(r, cc) * 8] =
          *(const bf16x8*)(Kh + (size_t)(kv0 + r) * 128 + cc * 8);
    }
#pragma unroll
    for (int i = 0; i < 4; ++i) {  // stage V^T tile: 128 rows x 8 chunks
      int c = tid + i * 256;
      int r = c >> 3, cc = c & 7;
      *(bf16x8*)&Vs[r * 64 + swz8(r, cc) * 8] =
          *(const bf16x8*)(Vh + (size_t)r * 2048 + kv0 + cc * 8);
    }
    __syncthreads();
    // S = Q K^T
    f32x4 s[4];
#pragma unroll
    for (int nf = 0; nf < 4; ++nf) s[nf] = FZ;
#pragma unroll
    for (int ks = 0; ks < 4; ++ks) {
#pragma unroll
      for (int nf = 0; nf < 4; ++nf) {
        int r = nf * 16 + lr;
        bf16x8 b = *(const bf16x8*)&Ks[r * 128 + swz16(r, ks * 4 + lkb) * 8];
        s[nf] = MFMA16(qf[ks], b, s[nf]);
      }
    }
    // scale + causal mask + online softmax (exp2 domain)
    float pmax[4];
#pragma unroll
    for (int r = 0; r < 4; ++r) pmax[r] = -__builtin_inff();
#pragma unroll
    for (int nf = 0; nf < 4; ++nf) {
      int colg = kv0 + nf * 16 + lr;
#pragma unroll
      for (int r = 0; r < 4; ++r) {
        int rowg = qrow + rb + r;
        float v = s[nf][r] * SCL;
        v = (colg > rowg) ? -__builtin_inff() : v;
        s[nf][r] = v;
        pmax[r] = fmaxf(pmax[r], v);
      }
    }
#pragma unroll
    for (int r = 0; r < 4; ++r) {  // reduce across the 16 lanes sharing these rows
      float v = pmax[r];
      v = fmaxf(v, __shfl_xor(v, 1, 64));
      v = fmaxf(v, __shfl_xor(v, 2, 64));
      v = fmaxf(v, __shfl_xor(v, 4, 64));
      v = fmaxf(v, __shfl_xor(v, 8, 64));
      pmax[r] = v;
    }
    float alpha[4];
#pragma unroll
    for (int r = 0; r < 4; ++r) {
      float mnew = fmaxf(mrun[r], pmax[r]);
      alpha[r] = exp2f(mrun[r] - mnew);
      mrun[r] = mnew;
    }
    float psum[4] = {0.f, 0.f, 0.f, 0.f};
#pragma unroll
    for (int nf = 0; nf < 4; ++nf)
#pragma unroll
      for (int r = 0; r < 4; ++r) {
        float p = exp2f(s[nf][r] - mrun[r]);
        s[nf][r] = p;
        psum[r] += p;
      }
#pragma unroll
    for (int r = 0; r < 4; ++r) {
      float v = psum[r];
      v += __shfl_xor(v, 1, 64);
      v += __shfl_xor(v, 2, 64);
      v += __shfl_xor(v, 4, 64);
      v += __shfl_xor(v, 8, 64);
      lrun[r] = lrun[r] * alpha[r] + v;
    }
#pragma unroll
    for (int nf = 0; nf < 8; ++nf) {
#pragma unroll
      for (int r = 0; r < 4; ++r) O[nf][r] *= alpha[r];
    }
    // P -> per-wave LDS (re-fragment for PV A-operand)
#pragma unroll
    for (int nf = 0; nf < 4; ++nf) {
#pragma unroll
      for (int r = 0; r < 4; ++r) {
        int row = rb + r;
        int col = nf * 16 + lr;
        Ps[wave * 1024 + row * 64 + swz8(row, col >> 3) * 8 + (col & 7)] = (bf16)s[nf][r];
      }
    }
    __syncthreads();
    // O += P @ V
#pragma unroll
    for (int ks2 = 0; ks2 < 2; ++ks2) {
      bf16x8 a = *(const bf16x8*)&Ps[wave * 1024 + lr * 64 + swz8(lr, ks2 * 4 + lkb) * 8];
#pragma unroll
      for (int nf = 0; nf < 8; ++nf) {
        int r = nf * 16 + lr;
        bf16x8 b = *(const bf16x8*)&Vs[r * 64 + swz8(r, ks2 * 4 + lkb) * 8];
        O[nf] = MFMA16(a, b, O[nf]);
      }
    }
  }
  // finalize phase B
#pragma unroll
  for (int r = 0; r < 4; ++r) {
    float inv = 1.f / lrun[r];
    int t = qrow + rb + r;
#pragma unroll
    for (int nf = 0; nf < 8; ++nf)
      Qw[(size_t)t * 128 + nf * 16 + lr] = (bf16)(O[nf][r] * inv);
  }
}

// ------- output projection: AO [bh][t][128] @ Wot [128][1024] + bo -> fp32 out ------
__global__ __launch_bounds__(256) void outproj_kernel(
    const bf16* __restrict__ AO, const bf16* __restrict__ Wot,
    const float* __restrict__ bo, float* __restrict__ out) {
  __shared__ __align__(16) bf16 As[64 * 128];
  __shared__ __align__(16) bf16 Bs[128 * 128];
  const f32x4 FZ = {0.f, 0.f, 0.f, 0.f};
  const int mt = blockIdx.x;
  const int tid = threadIdx.x, wave = tid >> 6, lane = tid & 63;
  const int lr = lane & 15, lkb = lane >> 4, rb = lkb * 4;
  const int wr = (wave >> 1) * 32, wc = (wave & 1) * 64;
  f32x4 acc[2][4];
#pragma unroll
  for (int mf = 0; mf < 2; ++mf)
#pragma unroll
    for (int nf = 0; nf < 4; ++nf) acc[mf][nf] = FZ;
  for (int kt = 0; kt < 8; ++kt) {  // kt == head index (k-chunk of 128)
    __syncthreads();
#pragma unroll
    for (int i = 0; i < 4; ++i) {
      int c = tid + i * 256;
      int r = c >> 4, cc = c & 15;
      int m = mt * 64 + r, bb = m >> 11, t = m & 2047;
      *(bf16x8*)&As[r * 128 + swz16(r, cc) * 8] =
          *(const bf16x8*)(AO + ((size_t)(bb * 8 + kt) * 2048 + t) * 128 + cc * 8);
    }
#pragma unroll
    for (int i = 0; i < 8; ++i) {
      int c = tid + i * 256;
      int r = c >> 4, cc = c & 15;
      *(bf16x8*)&Bs[r * 128 + swz16(r, cc) * 8] =
          *(const bf16x8*)(Wot + (size_t)r * 1024 + kt * 128 + cc * 8);
    }
    __syncthreads();
#pragma unroll
    for (int ks = 0; ks < 4; ++ks) {
      bf16x8 a0, a1;
      {
        int r = wr + lr;
        a0 = *(const bf16x8*)&As[r * 128 + swz16(r, ks * 4 + lkb) * 8];
        r = wr + 16 + lr;
        a1 = *(const bf16x8*)&As[r * 128 + swz16(r, ks * 4 + lkb) * 8];
      }
#pragma unroll
      for (int nf = 0; nf < 4; ++nf) {
        int r = wc + nf * 16 + lr;
        bf16x8 b = *(const bf16x8*)&Bs[r * 128 + swz16(r, ks * 4 + lkb) * 8];
        acc[0][nf] = MFMA16(a0, b, acc[0][nf]);
        acc[1][nf] = MFMA16(a1, b, acc[1][nf]);
      }
    }
  }
#pragma unroll
  for (int mf = 0; mf < 2; ++mf)
#pragma unroll
    for (int nf = 0; nf < 4; ++nf)
#pragma unroll
      for (int r = 0; r < 4; ++r) {
        int m = mt * 64 + wr + mf * 16 + rb + r;
        int n = wc + nf * 16 + lr;
        out[(size_t)m * 128 + n] = acc[mf][nf][r] + bo[n];
      }
}

extern "C" void kernel_launch(void* const* d_in, const int* in_sizes, int n_in,
                              void* d_out, int out_size, void* d_ws, size_t ws_size,
                              hipStream_t stream) {
  (void)in_sizes; (void)n_in; (void)out_size; (void)ws_size;
  const float* x  = (const float*)d_in[0];   // [4096][128] fp32
  const float* Wq = (const float*)d_in[1];   // [128][1024] fp32
  const float* Wk = (const float*)d_in[2];
  const float* Wv = (const float*)d_in[3];
  const float* Wo = (const float*)d_in[4];   // [1024][128] fp32
  const float* bo = (const float*)d_in[5];   // [128] fp32
  float* out = (float*)d_out;                // [4096][128] fp32

  // ws layout (bf16 elements): total 13,107,200 el = 25 MB
  bf16* ws  = (bf16*)d_ws;
  bf16* Wqt = ws;                 // [1024][128]
  bf16* Wkt = Wqt + 131072;
  bf16* Wvt = Wkt + 131072;
  bf16* Wot = Wvt + 131072;       // [128][1024]
  bf16* Qb  = Wot + 131072;       // [16][2048][128]; attn output written in-place
  bf16* Kb  = Qb + 4194304;       // [16][2048][128]
  bf16* Vt  = Kb + 4194304;       // [16][128][2048]

  tr_to_bf16_kernel<float><<<dim3(4, 32, 1), 256, 0, stream>>>(Wq, Wqt, 128, 1024);
  tr_to_bf16_kernel<float><<<dim3(4, 32, 1), 256, 0, stream>>>(Wk, Wkt, 128, 1024);
  tr_to_bf16_kernel<float><<<dim3(4, 32, 1), 256, 0, stream>>>(Wv, Wvt, 128, 1024);
  tr_to_bf16_kernel<float><<<dim3(32, 4, 1), 256, 0, stream>>>(Wo, Wot, 1024, 128);
  proj_gemm<<<dim3(32, 24, 1), 256, 0, stream>>>(x, Wqt, Wkt, Wvt, Qb, Kb, Vt);
  attn_kernel<<<dim3(256, 1, 1), 256, 0, stream>>>(Qb, Kb, Vt);
  outproj_kernel<<<dim3(64, 1, 1), 256, 0, stream>>>(Qb, Wot, bo, out);
}

// Round 4
// 159.775 us; speedup vs baseline: 1.1031x; 1.1031x over previous
//
#include <hip/hip_runtime.h>

typedef __bf16 bf16;
typedef __bf16 bf16x4 __attribute__((ext_vector_type(4)));
typedef __bf16 bf16x8 __attribute__((ext_vector_type(8)));
typedef float f32x4 __attribute__((ext_vector_type(4)));

#define MFMA16(a, b, c) __builtin_amdgcn_mfma_f32_16x16x32_bf16((a), (b), (c), 0, 0, 0)

__device__ __forceinline__ int swz16(int r, int c) { return (c ^ (r & 15)); }
__device__ __forceinline__ int swz8(int r, int c) { return (c ^ (r & 7)); }

// ---- fused transpose of Wq/Wk/Wv: out[z][c][r] = (bf16)in_z[r][c], 128x1024 each ----
__global__ __launch_bounds__(256) void tr3_kernel(
    const float* __restrict__ Wq, const float* __restrict__ Wk,
    const float* __restrict__ Wv, bf16* __restrict__ outbase) {
  __shared__ bf16 tile[32][33];
  const int z = blockIdx.z;
  const float* ib = (z == 0) ? Wq : (z == 1) ? Wk : Wv;
  bf16* ob = outbase + (size_t)z * 131072;
  int r0 = blockIdx.x * 32, c0 = blockIdx.y * 32;
  int tx = threadIdx.x & 31, ty = threadIdx.x >> 5;
#pragma unroll
  for (int i = 0; i < 4; ++i) {
    int r = ty + i * 8;
    tile[r][tx] = (bf16)ib[(size_t)(r0 + r) * 1024 + (c0 + tx)];
  }
  __syncthreads();
#pragma unroll
  for (int i = 0; i < 4; ++i) {
    int r = ty + i * 8;
    ob[(size_t)(c0 + r) * 128 + (r0 + tx)] = tile[tx][r];
  }
}

// ---- Wo transpose: out[c][r] = (bf16)in[r][c], 1024x128 -> 128x1024 ----
__global__ __launch_bounds__(256) void trWo_kernel(
    const float* __restrict__ in, bf16* __restrict__ out) {
  __shared__ bf16 tile[32][33];
  int r0 = blockIdx.x * 32, c0 = blockIdx.y * 32;
  int tx = threadIdx.x & 31, ty = threadIdx.x >> 5;
#pragma unroll
  for (int i = 0; i < 4; ++i) {
    int r = ty + i * 8;
    tile[r][tx] = (bf16)in[(size_t)(r0 + r) * 128 + (c0 + tx)];
  }
  __syncthreads();
#pragma unroll
  for (int i = 0; i < 4; ++i) {
    int r = ty + i * 8;
    out[(size_t)(c0 + r) * 1024 + (r0 + tx)] = tile[tx][r];
  }
}

// -------- QKV projection: fp32 x [4096x128] @ Wt -> Q/K [bh][t][d], V [bh][d][t] ----
__global__ __launch_bounds__(256) void proj_gemm(
    const float* __restrict__ x, const bf16* __restrict__ Wqt,
    const bf16* __restrict__ Wkt, const bf16* __restrict__ Wvt,
    bf16* __restrict__ Qb, bf16* __restrict__ Kb, bf16* __restrict__ Vt) {
  __shared__ __align__(16) bf16 As[128 * 128];
  __shared__ __align__(16) bf16 Bs[128 * 128];
  const int mt = blockIdx.x;  // 32 tiles of 128 token-rows
  const int nt = blockIdx.y;  // 24 tiles of 128 cols (8 per matrix)
  const int matid = nt >> 3, h = nt & 7;
  const bf16* W = (matid == 0) ? Wqt : (matid == 1) ? Wkt : Wvt;
  const int tid = threadIdx.x;
  const bf16* sb = W + (size_t)h * 128 * 128;
#pragma unroll
  for (int i = 0; i < 8; ++i) {  // stage x tile, fp32 -> bf16
    int c = tid + i * 256;
    int r = c >> 4, cc = c & 15;
    const f32x4* p = (const f32x4*)(x + (size_t)(mt * 128 + r) * 128 + cc * 8);
    f32x4 a = p[0], b = p[1];
    bf16x8 o;
#pragma unroll
    for (int j = 0; j < 4; ++j) { o[j] = (bf16)a[j]; o[4 + j] = (bf16)b[j]; }
    *(bf16x8*)&As[r * 128 + swz16(r, cc) * 8] = o;
  }
#pragma unroll
  for (int i = 0; i < 8; ++i) {
    int c = tid + i * 256;
    int r = c >> 4, cc = c & 15;
    *(bf16x8*)&Bs[r * 128 + swz16(r, cc) * 8] = *(const bf16x8*)(sb + (size_t)r * 128 + cc * 8);
  }
  __syncthreads();
  const int wave = tid >> 6, lane = tid & 63;
  const int wr = (wave >> 1) * 64, wc = (wave & 1) * 64;
  const int lr = lane & 15, lkb = lane >> 4;
  const f32x4 FZ = {0.f, 0.f, 0.f, 0.f};
  f32x4 acc[4][4];
#pragma unroll
  for (int mf = 0; mf < 4; ++mf)
#pragma unroll
    for (int nf = 0; nf < 4; ++nf) acc[mf][nf] = FZ;
  const bool qk = (matid < 2);
#pragma unroll
  for (int ks = 0; ks < 4; ++ks) {
    bf16x8 a[4], b[4];
#pragma unroll
    for (int mf = 0; mf < 4; ++mf) {
      int r = wr + mf * 16 + lr;
      a[mf] = *(const bf16x8*)&As[r * 128 + swz16(r, ks * 4 + lkb) * 8];
    }
#pragma unroll
    for (int nf = 0; nf < 4; ++nf) {
      int r = wc + nf * 16 + lr;
      b[nf] = *(const bf16x8*)&Bs[r * 128 + swz16(r, ks * 4 + lkb) * 8];
    }
    if (qk) {  // transposed output: C[row=n][col=m] -> vectorizable d-runs
#pragma unroll
      for (int mf = 0; mf < 4; ++mf)
#pragma unroll
        for (int nf = 0; nf < 4; ++nf) acc[mf][nf] = MFMA16(b[nf], a[mf], acc[mf][nf]);
    } else {
#pragma unroll
      for (int mf = 0; mf < 4; ++mf)
#pragma unroll
        for (int nf = 0; nf < 4; ++nf) acc[mf][nf] = MFMA16(a[mf], b[nf], acc[mf][nf]);
    }
  }
  const int rb = lkb * 4;
  if (qk) {  // Q/K: [bh][t][d]; lane holds 4 consecutive d for one token
    bf16* Out = (matid == 0) ? Qb : Kb;
#pragma unroll
    for (int mf = 0; mf < 4; ++mf)
#pragma unroll
      for (int nf = 0; nf < 4; ++nf) {
        int m = mt * 128 + wr + mf * 16 + lr;  // token
        int d0 = wc + nf * 16 + rb;            // 4 consecutive dims
        int bb = m >> 11, t = m & 2047;
        bf16x4 vv;
#pragma unroll
        for (int r = 0; r < 4; ++r) vv[r] = (bf16)acc[mf][nf][r];
        *(bf16x4*)(Out + ((size_t)(bb * 8 + h) * 2048 + t) * 128 + d0) = vv;
      }
  } else {  // V: [bh][d][t]; lane holds 4 consecutive tokens for one dim
#pragma unroll
    for (int mf = 0; mf < 4; ++mf)
#pragma unroll
      for (int nf = 0; nf < 4; ++nf) {
        int d = wc + nf * 16 + lr;
        int m0 = mt * 128 + wr + mf * 16 + rb;
        int bb = m0 >> 11, t0 = m0 & 2047;
        bf16x4 vv;
#pragma unroll
        for (int r = 0; r < 4; ++r) vv[r] = (bf16)acc[mf][nf][r];
        *(bf16x4*)(Vt + ((size_t)(bb * 8 + h) * 128 + d) * 2048 + t0) = vv;
      }
  }
}

// ---- causal flash attention: 512 blocks (one 64-row q-tile each), prefetched ----
__global__ __launch_bounds__(256, 3) void attn_kernel(
    bf16* __restrict__ Qb, const bf16* __restrict__ Kb, const bf16* __restrict__ Vt) {
  __shared__ __align__(16) bf16 Ks[64 * 128];     // [kv j][k], swizzled chunks
  __shared__ __align__(16) bf16 Vs[128 * 64];     // [d][kv j], swizzled chunks
  __shared__ __align__(16) bf16 Ps[4 * 16 * 64];  // per-wave P tile
  const f32x4 FZ = {0.f, 0.f, 0.f, 0.f};
  const int bid = blockIdx.x;
  const int qt = 31 - (bid >> 4);  // big tiles dispatched first (LPT)
  const int bh = bid & 15;
  const int nT = qt + 1;
  const bf16* Qh = Qb + (size_t)bh * 2048 * 128;
  bf16* Qw = Qb + (size_t)bh * 2048 * 128;
  const bf16* Kh = Kb + (size_t)bh * 2048 * 128;
  const bf16* Vh = Vt + (size_t)bh * 128 * 2048;
  const int tid = threadIdx.x, wave = tid >> 6, lane = tid & 63;
  const int lr = lane & 15, lkb = lane >> 4, rb = lkb * 4;
  const float SCL = 0.12751744f;  // log2(e)/sqrt(128)
  const int qrow = qt * 64 + wave * 16;

  // loop-invariant staging addresses
  const int krow = tid >> 4, kcc = tid & 15;
  bf16* kdst = &Ks[krow * 128 + (kcc ^ krow) * 8];
  const bf16* ksrc0 = Kh + (size_t)krow * 128 + kcc * 8;  // + kv0*128 + i*2048
  const int vrow = tid >> 3, vcc = tid & 7;
  bf16* vdst = &Vs[vrow * 64 + (vcc ^ (vrow & 7)) * 8];
  const bf16* vsrc0 = Vh + (size_t)vrow * 2048 + vcc * 8;  // + kv0 + i*65536

  float mrun[4], lrun[4];
  f32x4 O[8];
  bf16x8 qf[4];
#pragma unroll
  for (int r = 0; r < 4; ++r) { mrun[r] = -__builtin_inff(); lrun[r] = 0.f; }
#pragma unroll
  for (int nf = 0; nf < 8; ++nf) O[nf] = FZ;
#pragma unroll
  for (int ks = 0; ks < 4; ++ks)
    qf[ks] = *(const bf16x8*)(Qh + (size_t)(qrow + lr) * 128 + ks * 32 + lkb * 8);

  // prefetch tile 0
  bf16x8 kpre[4], vpre[4];
#pragma unroll
  for (int i = 0; i < 4; ++i) kpre[i] = *(const bf16x8*)(ksrc0 + i * 2048);
#pragma unroll
  for (int i = 0; i < 4; ++i) vpre[i] = *(const bf16x8*)(vsrc0 + i * 65536);

  for (int it = 0; it < nT; ++it) {
    __syncthreads();  // previous iteration's PV reads done
#pragma unroll
    for (int i = 0; i < 4; ++i) *(bf16x8*)(kdst + i * 2048) = kpre[i];
#pragma unroll
    for (int i = 0; i < 4; ++i) *(bf16x8*)(vdst + i * 2048) = vpre[i];
    __syncthreads();  // staged tile visible
    if (it + 1 < nT) {  // issue next tile's loads; land during compute
      const size_t koff = (size_t)(it + 1) * 8192;
      const size_t voff = (size_t)(it + 1) * 64;
#pragma unroll
      for (int i = 0; i < 4; ++i) kpre[i] = *(const bf16x8*)(ksrc0 + koff + i * 2048);
#pragma unroll
      for (int i = 0; i < 4; ++i) vpre[i] = *(const bf16x8*)(vsrc0 + voff + i * 65536);
    }
    // S = Q K^T (raw, unscaled)
    f32x4 s[4];
#pragma unroll
    for (int nf = 0; nf < 4; ++nf) s[nf] = FZ;
#pragma unroll
    for (int ks = 0; ks < 4; ++ks) {
#pragma unroll
      for (int nf = 0; nf < 4; ++nf) {
        int r = nf * 16 + lr;
        bf16x8 b = *(const bf16x8*)&Ks[r * 128 + swz16(r, ks * 4 + lkb) * 8];
        s[nf] = MFMA16(qf[ks], b, s[nf]);
      }
    }
    // raw-domain max (mask only on the diagonal tile; wave-uniform branch)
    float pmax[4];
#pragma unroll
    for (int r = 0; r < 4; ++r) pmax[r] = -__builtin_inff();
    if (it == qt) {
#pragma unroll
      for (int nf = 0; nf < 4; ++nf) {
        int colg = (qt << 6) + nf * 16 + lr;
#pragma unroll
        for (int r = 0; r < 4; ++r) {
          int rowg = qrow + rb + r;
          float v = (colg > rowg) ? -__builtin_inff() : s[nf][r];
          s[nf][r] = v;
          pmax[r] = fmaxf(pmax[r], v);
        }
      }
    } else {
#pragma unroll
      for (int nf = 0; nf < 4; ++nf)
#pragma unroll
        for (int r = 0; r < 4; ++r) pmax[r] = fmaxf(pmax[r], s[nf][r]);
    }
#pragma unroll
    for (int r = 0; r < 4; ++r) {  // reduce across the 16 lanes sharing these rows
      float v = pmax[r];
      v = fmaxf(v, __shfl_xor(v, 1, 64));
      v = fmaxf(v, __shfl_xor(v, 2, 64));
      v = fmaxf(v, __shfl_xor(v, 4, 64));
      v = fmaxf(v, __shfl_xor(v, 8, 64));
      pmax[r] = v;
    }
    float alpha[4];
#pragma unroll
    for (int r = 0; r < 4; ++r) {
      float mnew = fmaxf(mrun[r], pmax[r] * SCL);
      alpha[r] = exp2f(mrun[r] - mnew);
      mrun[r] = mnew;
    }
    float psum[4] = {0.f, 0.f, 0.f, 0.f};
#pragma unroll
    for (int nf = 0; nf < 4; ++nf)
#pragma unroll
      for (int r = 0; r < 4; ++r) {
        float p = exp2f(__builtin_fmaf(s[nf][r], SCL, -mrun[r]));
        s[nf][r] = p;
        psum[r] += p;
      }
#pragma unroll
    for (int r = 0; r < 4; ++r) {
      float v = psum[r];
      v += __shfl_xor(v, 1, 64);
      v += __shfl_xor(v, 2, 64);
      v += __shfl_xor(v, 4, 64);
      v += __shfl_xor(v, 8, 64);
      lrun[r] = lrun[r] * alpha[r] + v;
    }
#pragma unroll
    for (int nf = 0; nf < 8; ++nf) {
#pragma unroll
      for (int r = 0; r < 4; ++r) O[nf][r] *= alpha[r];
    }
    // P -> per-wave LDS (re-fragment for PV A-operand); wave-private, no barrier
#pragma unroll
    for (int nf = 0; nf < 4; ++nf) {
#pragma unroll
      for (int r = 0; r < 4; ++r) {
        int row = rb + r;
        int col = nf * 16 + lr;
        Ps[wave * 1024 + row * 64 + swz8(row, col >> 3) * 8 + (col & 7)] = (bf16)s[nf][r];
      }
    }
    // O += P @ V
#pragma unroll
    for (int ks2 = 0; ks2 < 2; ++ks2) {
      bf16x8 a = *(const bf16x8*)&Ps[wave * 1024 + lr * 64 + swz8(lr, ks2 * 4 + lkb) * 8];
#pragma unroll
      for (int nf = 0; nf < 8; ++nf) {
        int r = nf * 16 + lr;
        bf16x8 b = *(const bf16x8*)&Vs[r * 64 + swz8(r, ks2 * 4 + lkb) * 8];
        O[nf] = MFMA16(a, b, O[nf]);
      }
    }
  }
  // finalize: write attention output in place over this block's own Q rows
#pragma unroll
  for (int r = 0; r < 4; ++r) {
    float inv = 1.f / lrun[r];
    int t = qrow + rb + r;
#pragma unroll
    for (int nf = 0; nf < 8; ++nf)
      Qw[(size_t)t * 128 + nf * 16 + lr] = (bf16)(O[nf][r] * inv);
  }
}

// ------- output projection: AO [bh][t][128] @ Wot [128][1024] + bo -> fp32 out ------
__global__ __launch_bounds__(256) void outproj_kernel(
    const bf16* __restrict__ AO, const bf16* __restrict__ Wot,
    const float* __restrict__ bo, float* __restrict__ out) {
  __shared__ __align__(16) bf16 As[32 * 128];
  __shared__ __align__(16) bf16 Bs[128 * 128];
  const f32x4 FZ = {0.f, 0.f, 0.f, 0.f};
  const int mt = blockIdx.x;  // 128 tiles of 32 rows
  const int tid = threadIdx.x, wave = tid >> 6, lane = tid & 63;
  const int lr = lane & 15, lkb = lane >> 4, rb = lkb * 4;
  const int wr = (wave >> 1) * 16, wc = (wave & 1) * 64;
  f32x4 acc[4];
#pragma unroll
  for (int nf = 0; nf < 4; ++nf) acc[nf] = FZ;
  for (int kt = 0; kt < 8; ++kt) {  // kt == head index (k-chunk of 128)
    __syncthreads();
#pragma unroll
    for (int i = 0; i < 2; ++i) {
      int c = tid + i * 256;
      int r = c >> 4, cc = c & 15;
      int m = mt * 32 + r, bb = m >> 11, t = m & 2047;
      *(bf16x8*)&As[r * 128 + swz16(r, cc) * 8] =
          *(const bf16x8*)(AO + ((size_t)(bb * 8 + kt) * 2048 + t) * 128 + cc * 8);
    }
#pragma unroll
    for (int i = 0; i < 8; ++i) {
      int c = tid + i * 256;
      int r = c >> 4, cc = c & 15;
      *(bf16x8*)&Bs[r * 128 + swz16(r, cc) * 8] =
          *(const bf16x8*)(Wot + (size_t)r * 1024 + kt * 128 + cc * 8);
    }
    __syncthreads();
#pragma unroll
    for (int ks = 0; ks < 4; ++ks) {
      int ra = wr + lr;
      bf16x8 a = *(const bf16x8*)&As[ra * 128 + swz16(ra, ks * 4 + lkb) * 8];
#pragma unroll
      for (int nf = 0; nf < 4; ++nf) {
        int r = wc + nf * 16 + lr;
        bf16x8 b = *(const bf16x8*)&Bs[r * 128 + swz16(r, ks * 4 + lkb) * 8];
        acc[nf] = MFMA16(a, b, acc[nf]);
      }
    }
  }
#pragma unroll
  for (int nf = 0; nf < 4; ++nf)
#pragma unroll
    for (int r = 0; r < 4; ++r) {
      int m = mt * 32 + wr + rb + r;
      int n = wc + nf * 16 + lr;
      out[(size_t)m * 128 + n] = acc[nf][r] + bo[n];
    }
}

extern "C" void kernel_launch(void* const* d_in, const int* in_sizes, int n_in,
                              void* d_out, int out_size, void* d_ws, size_t ws_size,
                              hipStream_t stream) {
  (void)in_sizes; (void)n_in; (void)out_size; (void)ws_size;
  const float* x  = (const float*)d_in[0];   // [4096][128] fp32
  const float* Wq = (const float*)d_in[1];   // [128][1024] fp32
  const float* Wk = (const float*)d_in[2];
  const float* Wv = (const float*)d_in[3];
  const float* Wo = (const float*)d_in[4];   // [1024][128] fp32
  const float* bo = (const float*)d_in[5];   // [128] fp32
  float* out = (float*)d_out;                // [4096][128] fp32

  // ws layout (bf16 elements): total 13,107,200 el = 25 MB
  bf16* ws  = (bf16*)d_ws;
  bf16* Wqt = ws;                 // [3][1024][128] (q,k,v transposed weights)
  bf16* Wkt = Wqt + 131072;
  bf16* Wvt = Wkt + 131072;
  bf16* Wot = Wvt + 131072;       // [128][1024]
  bf16* Qb  = Wot + 131072;       // [16][2048][128]; attn output written in-place
  bf16* Kb  = Qb + 4194304;       // [16][2048][128]
  bf16* Vt  = Kb + 4194304;       // [16][128][2048]

  tr3_kernel<<<dim3(4, 32, 3), 256, 0, stream>>>(Wq, Wk, Wv, Wqt);
  trWo_kernel<<<dim3(32, 4, 1), 256, 0, stream>>>(Wo, Wot);
  proj_gemm<<<dim3(32, 24, 1), 256, 0, stream>>>(x, Wqt, Wkt, Wvt, Qb, Kb, Vt);
  attn_kernel<<<dim3(512, 1, 1), 256, 0, stream>>>(Qb, Kb, Vt);
  outproj_kernel<<<dim3(128, 1, 1), 256, 0, stream>>>(Qb, Wot, bo, out);
}